// Round 2
// baseline (723.157 us; speedup 1.0000x reference)
//
#include <hip/hip_runtime.h>
#include <math.h>

#define B_ 128
#define S_ 256
#define H_ 1024
#define E_ 512
#define V_ 32000
#define KZ (E_ + 2 * H_)   // 2560

typedef short s8v  __attribute__((ext_vector_type(8)));
typedef float f32x4 __attribute__((ext_vector_type(4)));
typedef unsigned short us4 __attribute__((ext_vector_type(4)));
typedef unsigned short us8 __attribute__((ext_vector_type(8)));

// f32 -> bf16 round-to-nearest-even (bit trick, matches hardware RNE)
__device__ __forceinline__ unsigned short f2bf(float f)
{
    union { float f; unsigned u; } v; v.f = f;
    unsigned r = v.u + 0x7fffu + ((v.u >> 16) & 1u);
    return (unsigned short)(r >> 16);
}

// ---------------------------------------------------------------- fused prep:
// embed gather + 4 bias broadcasts + A2 fragments for the x_emb K-region (kb 0..15)
__global__ __launch_bounds__(256) void prep_kernel(
    const int* __restrict__ x, const float* __restrict__ emb, float* __restrict__ x_emb,
    const float* __restrict__ b_dec, float* __restrict__ dwdec,
    const float* __restrict__ b_pos, float* __restrict__ dwpos,
    const float* __restrict__ b_ih, float* __restrict__ gi,
    const float* __restrict__ b_hh, float* __restrict__ gh,
    unsigned short* __restrict__ A2)
{
    int idx = blockIdx.x * 256 + threadIdx.x;
    if (idx < B_ * E_) { x_emb[idx] = emb[(size_t)x[idx >> 9] * E_ + (idx & 511)]; return; }
    idx -= B_ * E_;
    if (idx < B_ * H_) { dwdec[idx] = b_dec[idx & 1023]; return; }
    idx -= B_ * H_;
    if (idx < B_ * H_) { dwpos[idx] = b_pos[idx & 1023]; return; }
    idx -= B_ * H_;
    if (idx < B_ * 3 * H_) { gi[idx] = b_ih[idx % (3 * H_)]; return; }
    idx -= B_ * 3 * H_;
    if (idx < B_ * 3 * H_) { gh[idx] = b_hh[idx % (3 * H_)]; return; }
    idx -= B_ * 3 * H_;
    // idx in [0, 8192): A2 fragment (kb,mt,lane) for k in [0,512) read from emb directly
    int l  = idx & 63;
    int mt = (idx >> 6) & 7;
    int b  = mt * 16 + (l & 15);
    int k0 = (idx >> 9) * 32 + ((l >> 4) << 3);
    const float* p = emb + (size_t)x[b] * E_ + k0;
    us8 o;
    #pragma unroll
    for (int j = 0; j < 8; j++) o[j] = f2bf(p[j]);
    *(us8*)(A2 + (size_t)idx * 8) = o;
}

// ---------------------------------------------------------------- generic f32 GEMM core (mid GEMMs)
// C[m,n] += sum_k A[m,k] * W[n,k]    M=128 fixed, 256 threads, TILE_K=16
// CONCAT: A is the virtual concat [Aa (E_ cols) | Ab (H_ cols)]
template<int TILE_N, int MICRO_N, bool CONCAT>
__device__ __forceinline__ void gemm_core(const float* __restrict__ A,
                                          const float* __restrict__ Aa,
                                          const float* __restrict__ Ab,
                                          const float* __restrict__ W,
                                          float* __restrict__ C,
                                          int N, int K, int kbeg, int kend, int n0,
                                          float (*As)[132], float (*Ws)[TILE_N + 4])
{
    constexpr int NT_N   = TILE_N / MICRO_N;
    constexpr int NT_M   = 256 / NT_N;
    constexpr int MICRO_M = 128 / NT_M;
    const int tid = threadIdx.x;
    const int tn  = (tid % NT_N) * MICRO_N;
    const int tm  = (tid / NT_N) * MICRO_M;

    float acc[MICRO_M][MICRO_N] = {};

    for (int k0 = kbeg; k0 < kend; k0 += 16) {
        #pragma unroll
        for (int r = 0; r < 2; r++) {
            int v  = tid + 256 * r;
            int m  = v >> 2;
            int kk = (v & 3) << 2;
            int kcol = k0 + kk;
            float4 a4;
            if (CONCAT)
                a4 = (kcol < E_) ? *(const float4*)(Aa + (size_t)m * E_ + kcol)
                                 : *(const float4*)(Ab + (size_t)m * H_ + (kcol - E_));
            else
                a4 = *(const float4*)(A + (size_t)m * K + kcol);
            As[kk + 0][m] = a4.x; As[kk + 1][m] = a4.y;
            As[kk + 2][m] = a4.z; As[kk + 3][m] = a4.w;
        }
        for (int v = tid; v < TILE_N * 4; v += 256) {
            int n  = v >> 2;
            int kk = (v & 3) << 2;
            float4 w4 = *(const float4*)(W + (size_t)(n0 + n) * K + k0 + kk);
            Ws[kk + 0][n] = w4.x; Ws[kk + 1][n] = w4.y;
            Ws[kk + 2][n] = w4.z; Ws[kk + 3][n] = w4.w;
        }
        __syncthreads();
        #pragma unroll
        for (int kk = 0; kk < 16; kk++) {
            float a[MICRO_M], w[MICRO_N];
            #pragma unroll
            for (int i = 0; i < MICRO_M; i++) a[i] = As[kk][tm + i];
            #pragma unroll
            for (int j = 0; j < MICRO_N; j++) w[j] = Ws[kk][tn + j];
            #pragma unroll
            for (int i = 0; i < MICRO_M; i++)
                #pragma unroll
                for (int j = 0; j < MICRO_N; j++)
                    acc[i][j] = fmaf(a[i], w[j], acc[i][j]);
        }
        __syncthreads();
    }

    #pragma unroll
    for (int i = 0; i < MICRO_M; i++)
        #pragma unroll
        for (int j = 0; j < MICRO_N; j++)
            atomicAdd(C + (size_t)(tm + i) * N + n0 + tn + j, acc[i][j]);
}

// ---------------------------------------------------------------- MFMA z-part core
// C[m, n] (+)= sum over kb in [kb0, kb0+nkb) of A[m,k]*W[n,k]; A2 is bf16 in
// fragment order; W f32 reg-staged -> bf16 into a 4-deep LDS ring, 2-ahead
// prefetch, drain-free barriers (prefetch stays in flight across s_barrier).
__device__ __forceinline__ void zpart(const unsigned short* __restrict__ A2,
                                      const float* __restrict__ W,
                                      const float* __restrict__ bias,
                                      float* __restrict__ C,
                                      int blk, int kb0, int nkb, bool first,
                                      unsigned short (*Ws)[2560])
{
    const int tid  = threadIdx.x;
    const int n0   = blk * 64;
    const int w    = tid >> 6;
    const int lane = tid & 63;
    const int quad = lane >> 4;
    const int l16  = lane & 15;

    const int sn0 = tid >> 3;
    const int sk  = (tid & 7) << 2;
    const float* wp0 = W + (size_t)(n0 + sn0) * KZ + kb0 * 32 + sk;
    const float* wp1 = W + (size_t)(n0 + sn0 + 32) * KZ + kb0 * 32 + sk;
    const int wsoff0 = sn0 * 40 + sk;
    const int wsoff1 = (sn0 + 32) * 40 + sk;
    const unsigned short* ap = A2 + (size_t)kb0 * 4096 + lane * 8;
    const int boff = (w * 16 + l16) * 40 + quad * 8;

    float4 wA[2], wB[2];
    f32x4 acc[8] = {};

    auto ldw = [&](int t, float4 (&r)[2]) {
        r[0] = *(const float4*)(wp0 + t * 32);
        r[1] = *(const float4*)(wp1 + t * 32);
    };
    auto stw = [&](int buf, const float4 (&r)[2]) {
        us4 p0, p1;
        p0.x = f2bf(r[0].x); p0.y = f2bf(r[0].y); p0.z = f2bf(r[0].z); p0.w = f2bf(r[0].w);
        p1.x = f2bf(r[1].x); p1.y = f2bf(r[1].y); p1.z = f2bf(r[1].z); p1.w = f2bf(r[1].w);
        *(us4*)&Ws[buf][wsoff0] = p0;
        *(us4*)&Ws[buf][wsoff1] = p1;
    };
    auto barrier = [&]() {
        asm volatile("s_waitcnt lgkmcnt(0)" ::: "memory");
        __builtin_amdgcn_s_barrier();
        asm volatile("" ::: "memory");
    };
    auto subiter = [&](int t, float4 (&wLd)[2], const float4 (&wSt)[2]) {
        s8v af[8];
        const unsigned short* ab = ap + (size_t)t * 4096;
        #pragma unroll
        for (int mt = 0; mt < 8; mt++) af[mt] = *(const s8v*)(ab + mt * 512);
        if (t + 2 < nkb) ldw(t + 2, wLd);
        s8v bfrag = *(const s8v*)&Ws[t & 3][boff];
        #pragma unroll
        for (int mt = 0; mt < 8; mt++)
            acc[mt] = __builtin_amdgcn_mfma_f32_16x16x32_bf16(af[mt], bfrag, acc[mt], 0, 0, 0);
        if (t + 1 < nkb) stw((t + 1) & 3, wSt);
        barrier();
    };

    ldw(0, wA); ldw(1, wB);
    stw(0, wA);
    barrier();

    #pragma unroll 1
    for (int t = 0; t < nkb; t += 2) {
        subiter(t,     wA, wB);
        subiter(t + 1, wB, wA);
    }

    const int n = n0 + w * 16 + l16;
    if (first) {
        const float bv = bias[n];
        #pragma unroll
        for (int mt = 0; mt < 8; mt++)
            #pragma unroll
            for (int r = 0; r < 4; r++)
                C[(size_t)(mt * 16 + quad * 4 + r) * V_ + n] = acc[mt][r] + bv;
    } else {
        #pragma unroll
        for (int mt = 0; mt < 8; mt++)
            #pragma unroll
            for (int r = 0; r < 4; r++)
                C[(size_t)(mt * 16 + quad * 4 + r) * V_ + n] += acc[mt][r];
    }
}

// ---------------------------------------------------------------- fused launch 2:
// dual1 (dwdec,dwpos; latency-bound) co-runs with z-part1 (x_emb K-region, 65.5 MB W_fc)
__global__ __launch_bounds__(256) void fused_d1z1(
    const float* __restrict__ phd,
    const float* __restrict__ W_dec, float* __restrict__ dwdec,
    const float* __restrict__ W_pos, float* __restrict__ dwpos,
    const unsigned short* __restrict__ A2, const float* __restrict__ W_fc,
    const float* __restrict__ b_fc, float* __restrict__ out_z)
{
    __shared__ float As[16][132];
    __shared__ float Wsf[16][36];
    __shared__ unsigned short Wz[4][2560];
    int id = blockIdx.x;
    if (id < 256) {
        int xb = id & 31, yb = (id >> 5) & 3, zb = id >> 7;
        if (zb == 0)
            gemm_core<32, 2, false>(phd, nullptr, nullptr, W_dec, dwdec, H_, H_,
                                    yb * 256, yb * 256 + 256, xb * 32, As, Wsf);
        else
            gemm_core<32, 2, false>(phd, nullptr, nullptr, W_pos, dwpos, H_, H_,
                                    yb * 256, yb * 256 + 256, xb * 32, As, Wsf);
    } else {
        zpart(A2, W_fc, b_fc, out_z, id - 256, 0, 16, true, Wz);
    }
}

// ---------------------------------------------------------------- fused launch 5:
// dual2 (gi,gh) co-runs with z-part3 (ctx K-region, 131 MB W_fc)
__global__ __launch_bounds__(256) void fused_d2z3(
    const float* __restrict__ x_emb, const float* __restrict__ ctx,
    const float* __restrict__ W_ih, float* __restrict__ gi,
    const float* __restrict__ phd, const float* __restrict__ W_hh, float* __restrict__ gh,
    const unsigned short* __restrict__ A2, const float* __restrict__ W_fc,
    float* __restrict__ out_z)
{
    __shared__ float As[16][132];
    __shared__ float Wsf[16][36];
    __shared__ unsigned short Wz[4][2560];
    int id = blockIdx.x;
    if (id < 768) {
        int xb = id % 96, yb = (id / 96) & 3, zb = id / 384;
        if (zb == 0)
            gemm_core<32, 2, true>(nullptr, x_emb, ctx, W_ih, gi, 3 * H_, E_ + H_,
                                   yb * 384, yb * 384 + 384, xb * 32, As, Wsf);
        else
            gemm_core<32, 2, false>(phd, nullptr, nullptr, W_hh, gh, 3 * H_, H_,
                                    yb * 256, yb * 256 + 256, xb * 32, As, Wsf);
    } else {
        zpart(A2, W_fc, nullptr, out_z, id - 768, 48, 32, false, Wz);
    }
}

// ---------------------------------------------------------------- z-part2 (h_new K-region)
__global__ __launch_bounds__(256) void zpart_kernel(const unsigned short* __restrict__ A2,
                                                    const float* __restrict__ W_fc,
                                                    float* __restrict__ out_z)
{
    __shared__ unsigned short Wz[4][2560];
    zpart(A2, W_fc, nullptr, out_z, blockIdx.x, 16, 32, false, Wz);
}

// ---------------------------------------------------------------- energy[s,b] = masked tanh(dw[b].enc[s,b])
__global__ __launch_bounds__(256) void energy_kernel(const float* __restrict__ dw,
                                                     const float* __restrict__ enc,
                                                     const int* __restrict__ masks,
                                                     float* __restrict__ energy)
{
    int wid  = (blockIdx.x << 2) + (threadIdx.x >> 6);  // wid = s*B + b
    int lane = threadIdx.x & 63;
    int b    = wid & (B_ - 1);
    const float4* ep = (const float4*)(enc + (size_t)wid * H_);
    const float4* dp = (const float4*)(dw + (size_t)b * H_);
    float acc = 0.f;
    #pragma unroll
    for (int i = 0; i < 4; i++) {
        float4 a = dp[lane + (i << 6)];
        float4 e = ep[lane + (i << 6)];
        acc += a.x * e.x + a.y * e.y + a.z * e.z + a.w * e.w;
    }
    for (int off = 32; off; off >>= 1) acc += __shfl_down(acc, off, 64);
    if (lane == 0)
        energy[wid] = masks[wid] ? tanhf(acc) : -1e30f;
}

// ---------------------------------------------------------------- fused attention tail:
// per-b block: pt + softmax*window + context + ctx A2-fragments (kb 48..79)
__global__ __launch_bounds__(256) void attn2(const float* __restrict__ energy,
                                             const int* __restrict__ masks,
                                             const float* __restrict__ dwpos,
                                             const float* __restrict__ w_proj,
                                             const float* __restrict__ enc,
                                             float* __restrict__ ctx,
                                             unsigned short* __restrict__ A2)
{
    __shared__ float sred[4];
    __shared__ int   sredi[4];
    __shared__ float w_lds[S_];
    __shared__ float ctx_lds[H_];
    __shared__ float s_pt;
    int b = blockIdx.x, tid = threadIdx.x;
    int lane = tid & 63, wv = tid >> 6;

    // pt: first-zero of mask column + w_proj . tanh(dwpos[b])
    int first = (masks[tid * B_ + b] == 0) ? tid : S_;
    for (int off = 32; off; off >>= 1) first = min(first, __shfl_down(first, off, 64));
    if (lane == 0) sredi[wv] = first;
    float sum = 0.f;
    for (int i = tid; i < H_; i += 256) sum += w_proj[i] * tanhf(dwpos[(size_t)b * H_ + i]);
    for (int off = 32; off; off >>= 1) sum += __shfl_down(sum, off, 64);
    if (lane == 0) sred[wv] = sum;
    __syncthreads();
    if (tid == 0) {
        int   fz  = min(min(sredi[0], sredi[1]), min(sredi[2], sredi[3]));
        float tot = sred[0] + sred[1] + sred[2] + sred[3];
        s_pt = ((float)fz - 1.f) * (1.f / (1.f + expf(-tot)));
    }
    __syncthreads();
    float ptb = s_pt;

    // softmax over s (tid == s) with local window
    float e = energy[tid * B_ + b];
    float m = e;
    for (int off = 32; off; off >>= 1) m = fmaxf(m, __shfl_down(m, off, 64));
    if (lane == 0) sred[wv] = m;
    __syncthreads();
    m = fmaxf(fmaxf(sred[0], sred[1]), fmaxf(sred[2], sred[3]));
    __syncthreads();
    float ex = expf(e - m);
    float l = ex;
    for (int off = 32; off; off >>= 1) l += __shfl_down(l, off, 64);
    if (lane == 0) sred[wv] = l;
    __syncthreads();
    l = sred[0] + sred[1] + sred[2] + sred[3];

    float fs   = (float)tid;
    float pmax = floorf(ptb + 5.f);
    float pmin = floorf(fmaxf(ptb - 5.f, 0.f));
    float d    = ptb - fs;
    float win  = ((fs < pmax) && (fs >= pmin)) ? expf(-(d * d) * (1.f / 12.5f)) : 0.f;
    w_lds[tid] = (ex / l) * win;
    __syncthreads();

    // context over the sparse window; stage ctx row in LDS for fragment emit
    int smin = (int)floorf(fmaxf(ptb - 5.f, 0.f));
    int smax = min((int)floorf(ptb + 5.f), S_);
    for (int h = tid; h < H_; h += 256) {
        float acc = 0.f;
        for (int s = smin; s < smax; s++)
            acc += w_lds[s] * enc[((size_t)s * B_ + b) * H_ + h];
        ctx[(size_t)b * H_ + h] = acc;
        ctx_lds[h] = acc;
    }
    __syncthreads();

    // A2 fragments for the ctx K-region: kb in [48,80), this block owns (mt,l16)=(b>>4,b&15)
    if (tid < 128) {
        int kb = 48 + (tid >> 2);
        int hi = tid & 3;
        int i0 = (tid >> 2) * 32 + hi * 8;
        us8 o;
        #pragma unroll
        for (int j = 0; j < 8; j++) o[j] = f2bf(ctx_lds[i0 + j]);
        *(us8*)(A2 + ((size_t)(kb * 8 + (b >> 4)) * 64 + hi * 16 + (b & 15)) * 8) = o;
    }
}

// ---------------------------------------------------------------- GRU epilogue + h_new A2-fragments (kb 16..47)
__global__ __launch_bounds__(256) void gru_concat(const float* __restrict__ gi,
                                                  const float* __restrict__ gh,
                                                  const float* __restrict__ phd,
                                                  float* __restrict__ out_h,
                                                  unsigned short* __restrict__ A2)
{
    int gid = blockIdx.x * 256 + threadIdx.x;   // 32*8*64 = 16384
    int l   = gid & 63;
    int mt  = (gid >> 6) & 7;
    int kbr = gid >> 9;                          // [0,32)
    int b   = mt * 16 + (l & 15);
    int i0  = kbr * 32 + ((l >> 4) << 3);        // [0,1024)

    const float* gib = gi + (size_t)b * 3 * H_ + i0;
    const float* ghb = gh + (size_t)b * 3 * H_ + i0;
    const float* ph  = phd + (size_t)b * H_ + i0;
    float* oh = out_h + (size_t)b * H_ + i0;
    us8 o;
    #pragma unroll
    for (int j = 0; j < 8; j++) {
        float ir = gib[j], iz = gib[H_ + j], in_ = gib[2 * H_ + j];
        float hr = ghb[j], hz = ghb[H_ + j], hn  = ghb[2 * H_ + j];
        float r  = 1.f / (1.f + expf(-(ir + hr)));
        float zg = 1.f / (1.f + expf(-(iz + hz)));
        float n  = tanhf(in_ + r * hn);
        float h  = (1.f - zg) * n + zg * ph[j];
        oh[j] = h;
        o[j] = f2bf(h);
    }
    *(us8*)(A2 + (size_t)(8192 + gid) * 8) = o;   // kb = 16 + kbr
}

// ---------------------------------------------------------------- launch
extern "C" void kernel_launch(void* const* d_in, const int* in_sizes, int n_in,
                              void* d_out, int out_size, void* d_ws, size_t ws_size,
                              hipStream_t stream)
{
    const int*   x      = (const int*)  d_in[0];
    const float* phd    = (const float*)d_in[1];   // (1,B,H)
    const float* enc    = (const float*)d_in[2];   // (S,B,H)
    const int*   masks  = (const int*)  d_in[3];   // (S,B)
    const float* emb    = (const float*)d_in[4];
    const float* W_dec  = (const float*)d_in[5];
    const float* b_dec  = (const float*)d_in[6];
    const float* W_pos  = (const float*)d_in[7];
    const float* b_pos  = (const float*)d_in[8];
    const float* w_proj = (const float*)d_in[9];
    const float* W_ih   = (const float*)d_in[10];
    const float* b_ih   = (const float*)d_in[11];
    const float* W_hh   = (const float*)d_in[12];
    const float* b_hh   = (const float*)d_in[13];
    const float* W_fc   = (const float*)d_in[14];
    const float* b_fc   = (const float*)d_in[15];

    float* out_z = (float*)d_out;                   // (1,B,V)
    float* out_h = out_z + (size_t)B_ * V_;         // (1,B,H)

    float* ws       = (float*)d_ws;
    float* x_emb    = ws;  ws += B_ * E_;
    float* dwdec    = ws;  ws += B_ * H_;
    float* dwpos    = ws;  ws += B_ * H_;
    float* energy   = ws;  ws += S_ * B_;
    float* ctx      = ws;  ws += B_ * H_;
    float* gi       = ws;  ws += B_ * 3 * H_;
    float* gh       = ws;  ws += B_ * 3 * H_;
    unsigned short* A2 = (unsigned short*)ws;       // B*KZ bf16, fragment order

    // L1: embed + bias inits + A2 x_emb fragments   (1,122,304 threads)
    prep_kernel<<<4384, 256, 0, stream>>>(x, emb, x_emb, b_dec, dwdec, b_pos, dwpos,
                                          b_ih, gi, b_hh, gh, A2);

    // L2: dual1 (256 blocks) || z-part1 (500 blocks, writes bias + x_emb partial)
    fused_d1z1<<<756, 256, 0, stream>>>(phd, W_dec, dwdec, W_pos, dwpos,
                                        A2, W_fc, b_fc, out_z);

    // L3: energy (134 MB enc stream)
    energy_kernel<<<S_ * B_ / 4, 256, 0, stream>>>(dwdec, enc, masks, energy);

    // L4: pt + softmax*window + context + ctx A2 fragments
    attn2<<<B_, 256, 0, stream>>>(energy, masks, dwpos, w_proj, enc, ctx, A2);

    // L5: dual2 (768 blocks) || z-part3 (500 blocks, += ctx partial)
    fused_d2z3<<<1268, 256, 0, stream>>>(x_emb, ctx, W_ih, gi, phd, W_hh, gh,
                                         A2, W_fc, out_z);

    // L6: GRU + h_new A2 fragments + out_h
    gru_concat<<<64, 256, 0, stream>>>(gi, gh, phd, out_h, A2);

    // L7: z-part2 (+= h_new partial) — only exposed W_fc stream (131 MB)
    zpart_kernel<<<500, 256, 0, stream>>>(A2, W_fc, out_z);
}